// Round 2
// baseline (8173.661 us; speedup 1.0000x reference)
//
#include <hip/hip_runtime.h>
#include <hip/hip_bf16.h>

// One block per batch element (256 blocks x 512 threads). All activations in
// dynamic LDS (~100KB -> 1 block/CU). Batch elems independent; GRU recurrence
// block-local. FULL F32 pipeline (R2: removed all f16 — R1's 0.228 absmax was
// f16 compounding through the 64-step x 8-layer recurrence).
//
// Collapsed MHA: _ff only needs sum(mha_out):
//   sum = sum_{h,c} (sum_s colsum_a[h,s]*v[s,h,c])*woSum[h,c] + S*boSum.

#define TPB 512

// ---- LDS layout (float slots) ----
constexpr int O_LAST = 0;            // 4096 : last / d1   [p*64+d]
constexpr int O_D0T  = 4096;         // 4160 : d0 transposed f32 [d*65 + p]
constexpr int O_BIG  = 8256;         // 8320 : cc (100x64) / ap (128x64), stride 65
constexpr int O_SCR  = 16576;        // 7424 : stage-disjoint scratch
constexpr int O_MST  = 24000;        // 1024 : mstate -> final GRU states [(i*2+dir)*64+j]
constexpr int O_RED  = 25024;        // 128  : small reductions
constexpr int SMF    = 25152;        // 100,608 bytes

// O_SCR sub-regions (stage-disjoint):
constexpr int C4P   = O_SCR;         // conv: c4 partials (2048)
constexpr int C3P   = O_SCR + 2048;  // conv: c3 partials (2048)
constexpr int WHO   = O_SCR + 3072;  // mha: staged W slice (1536, aliases PBUF)
constexpr int PBUF  = O_SCR + 3072;  // mha: exp(score) chunk 32x128 (4096)
constexpr int COLS  = O_SCR + 7168;  // mha: colsum_a (128)
constexpr int XGR   = O_SCR;         // gru: xg ring, 4 slots x 384 (1536)
constexpr int HBUF  = O_SCR + 1536;  // gru: h state f32, 2 dirs x 64 (128)

// O_RED sub-slots:
constexpr int LINV = O_RED;          // 32
constexpr int WOS  = O_RED + 32;     // 64
constexpr int BOS  = O_RED + 96;
constexpr int ACCS = O_RED + 97;
constexpr int SVV  = O_RED + 104;    // 8
constexpr int HSW  = O_RED + 112;    // 8
constexpr int HSV  = O_RED + 120;

template<int BF> __device__ __forceinline__ float ldf(const void* p, long i){
  if (BF){ unsigned v = ((unsigned)((const unsigned short*)p)[i]) << 16;
           return __builtin_bit_cast(float, v); }
  return ((const float*)p)[i];
}
template<int BF> __device__ __forceinline__ void ldw4(const void* p, long i,
                                                      float&a,float&b,float&c,float&d){
  if (BF){ uint2 u = *(const uint2*)((const unsigned short*)p + i);
    a=__builtin_bit_cast(float, u.x<<16); b=__builtin_bit_cast(float, u.x&0xFFFF0000u);
    c=__builtin_bit_cast(float, u.y<<16); d=__builtin_bit_cast(float, u.y&0xFFFF0000u);
  } else { float4 f = *(const float4*)((const float*)p + i); a=f.x;b=f.y;c=f.z;d=f.w; }
}
template<int BF> __device__ __forceinline__ void stf(void* p, long i, float v){
  if (BF){ unsigned u=__builtin_bit_cast(unsigned,v);
           u += 0x7FFFu + ((u>>16)&1u);
           ((unsigned short*)p)[i]=(unsigned short)(u>>16); }
  else ((float*)p)[i]=v;
}

// ---------------- MHA (collapsed) + ff + LN ----------------
// jj==0: X=cc (S=100), residual=O_LAST, out=O_D0T (transposed f32)
// jj==1: X=ap (S=128), residual=O_D0T,  out=O_LAST (d1)
template<int BF> __device__ void mha_ff_ln(float* sm, int li, int jj, int S,
    const void* qw, const void* qb, const void* ow, const void* ob,
    const void* ffw, const void* ang, const void* anb)
{
  const int tid = threadIdx.x;
  const int b2  = li*2 + jj;

  if (tid < 64){
    float s = 0; long wb = ((long)b2*64 + tid)*64;
    #pragma unroll 4
    for (int d=0; d<64; d+=4){ float a0,a1,a2,a3; ldw4<BF>(ow, wb+d, a0,a1,a2,a3); s += a0+a1+a2+a3; }
    sm[WOS+tid] = s;
  } else if (tid == 64){
    float s = 0; long bb = (long)b2*64;
    for (int d=0; d<64; ++d) s += ldf<BF>(ob, bb+d);
    sm[BOS] = s;
  } else if (tid == 65){ sm[ACCS] = 0.f; }
  __syncthreads();

  for (int h=0; h<8; ++h){
    if (tid < 384){
      int m = tid>>7, rem = tid&127, d = rem>>1, c0 = (rem&1)*4;
      long src = ((long)(b2*3+m))*4096 + (long)d*64 + h*8 + c0;
      float a0,a1,a2,a3; ldw4<BF>(qw, src, a0,a1,a2,a3);
      float* W = sm + WHO + m*512 + d*8 + c0; W[0]=a0; W[1]=a1; W[2]=a2; W[3]=a3;
    }
    for (int ss=tid; ss<S; ss+=TPB) sm[COLS+ss] = 0.f;
    __syncthreads();

    // q/k/v head slices: (m, s, c-quad)
    { int S2 = S*2, tot = 3*S2;
      for (int tk=tid; tk<tot; tk+=TPB){
        int m = (tk>=2*S2)?2:((tk>=S2)?1:0);
        int rem = tk - m*S2, s = rem>>1, c0 = (rem&1)*4;
        long bb = (long)(b2*3+m)*64 + h*8 + c0;
        float a0=ldf<BF>(qb,bb), a1=ldf<BF>(qb,bb+1), a2=ldf<BF>(qb,bb+2), a3=ldf<BF>(qb,bb+3);
        const float*  Xr = sm + O_BIG + s*65;
        const float4* Wv = (const float4*)(sm + WHO + m*512 + c0);
        #pragma unroll 8
        for (int d=0; d<64; ++d){ float xv = Xr[d]; float4 w = Wv[2*d];
          a0 += xv*w.x; a1 += xv*w.y; a2 += xv*w.z; a3 += xv*w.w; }
        float* dst = sm + O_SCR + m*1024 + s*8 + c0;
        dst[0]=a0; dst[1]=a1; dst[2]=a2; dst[3]=a3;
      } }
    __syncthreads();

    for (int q0=0; q0<S; q0+=32){
      int CH = (S-q0 < 32) ? (S-q0) : 32;
      { int ss = tid&127, cq0 = tid>>7;
        if (ss < S){
          const float* KH = sm + O_SCR + 1024;
          float4 k0 = *(const float4*)(KH + ss*8), k1 = *(const float4*)(KH + ss*8 + 4);
          for (int cq=cq0; cq<CH; cq+=4){
            const float* qv = sm + O_SCR + (q0+cq)*8;
            float dv = qv[0]*k0.x+qv[1]*k0.y+qv[2]*k0.z+qv[3]*k0.w
                     + qv[4]*k1.x+qv[5]*k1.y+qv[6]*k1.z+qv[7]*k1.w;
            sm[PBUF + cq*128 + ss] = __expf(dv*0.35355339059327378f);
          } } }
      __syncthreads();
      { int cq = tid>>4, l = tid&15;
        if (cq < CH){ float s = 0;
          for (int ss=l; ss<S; ss+=16) s += sm[PBUF + cq*128 + ss];
          s += __shfl_xor(s,8); s += __shfl_xor(s,4); s += __shfl_xor(s,2); s += __shfl_xor(s,1);
          if (l==0) sm[LINV+cq] = 1.f/s; } }
      __syncthreads();
      if (tid < S){ float a = sm[COLS+tid];
        for (int cq=0; cq<CH; ++cq) a += sm[PBUF + cq*128 + tid]*sm[LINV+cq];
        sm[COLS+tid] = a; }
      __syncthreads();
    }

    { int c = tid>>6, l = tid&63;
      const float* VH = sm + O_SCR + 2048;
      float pv = 0;
      if (l    < S) pv += sm[COLS+l   ]*VH[ l    *8 + c];
      if (l+64 < S) pv += sm[COLS+l+64]*VH[(l+64)*8 + c];
      pv += __shfl_xor(pv,32); pv += __shfl_xor(pv,16); pv += __shfl_xor(pv,8);
      pv += __shfl_xor(pv,4);  pv += __shfl_xor(pv,2);  pv += __shfl_xor(pv,1);
      if (l==0) sm[SVV+c] = pv; }
    __syncthreads();
    if (tid == 0){ float a = sm[ACCS];
      for (int c=0; c<8; ++c) a += sm[SVV+c]*sm[WOS + h*8 + c];
      sm[ACCS] = a; }
    __syncthreads();
  }

  const float s_scalar = sm[ACCS] + (float)S*sm[BOS];

  float part = 0;
  { long fb = (long)(b2*2)*4096;
    for (int q4=tid; q4<1024; q4+=TPB){
      float a0,a1,a2,a3; ldw4<BF>(ffw, fb + (long)q4*4, a0,a1,a2,a3);
      part += fmaxf(s_scalar*a0,0.f)+fmaxf(s_scalar*a1,0.f)
            + fmaxf(s_scalar*a2,0.f)+fmaxf(s_scalar*a3,0.f); } }
  part += __shfl_xor(part,32); part += __shfl_xor(part,16); part += __shfl_xor(part,8);
  part += __shfl_xor(part,4);  part += __shfl_xor(part,2);  part += __shfl_xor(part,1);
  if ((tid&63)==0) sm[HSW + (tid>>6)] = part;
  __syncthreads();
  if (tid == 0){ float v=0; for (int w=0;w<8;++w) v += sm[HSW+w]; sm[HSV]=v; }
  __syncthreads();
  const float hs = sm[HSV];

  // LN rows: 64 rows x 8 threads
  { int r = tid>>3, prt = tid&7;
    long f1b = (long)(b2*2+1)*4096 + r*64 + prt*8;
    float rs[8];
    if (jj == 0){
      const float* R = sm + O_LAST + r*64 + prt*8;
      #pragma unroll
      for (int e=0;e<8;++e) rs[e] = R[e];
    } else {
      #pragma unroll
      for (int e=0;e<8;++e) rs[e] = sm[O_D0T + (prt*8+e)*65 + r];
    }
    float w[8];
    ldw4<BF>(ffw, f1b,   w[0],w[1],w[2],w[3]);
    ldw4<BF>(ffw, f1b+4, w[4],w[5],w[6],w[7]);
    float f[8]; float s1=0, s2=0;
    #pragma unroll
    for (int e=0;e<8;++e){ float fv = hs*w[e] + rs[e]; f[e]=fv; s1+=fv; s2+=fv*fv; }
    s1 += __shfl_xor(s1,4); s1 += __shfl_xor(s1,2); s1 += __shfl_xor(s1,1);
    s2 += __shfl_xor(s2,4); s2 += __shfl_xor(s2,2); s2 += __shfl_xor(s2,1);
    float mean = s1*0.015625f, var = s2*0.015625f - mean*mean;
    float rstd = rsqrtf(var + 1e-3f);
    long gb2 = (long)b2*64 + prt*8;
    float g[8], bbv[8];
    ldw4<BF>(ang, gb2,   g[0],g[1],g[2],g[3]);   ldw4<BF>(ang, gb2+4, g[4],g[5],g[6],g[7]);
    ldw4<BF>(anb, gb2,   bbv[0],bbv[1],bbv[2],bbv[3]); ldw4<BF>(anb, gb2+4, bbv[4],bbv[5],bbv[6],bbv[7]);
    if (jj == 0){
      #pragma unroll
      for (int e=0;e<8;++e) sm[O_D0T + (prt*8+e)*65 + r] = (f[e]-mean)*rstd*g[e] + bbv[e];
    } else {
      float* dst = sm + O_LAST + r*64 + prt*8;
      #pragma unroll
      for (int e=0;e<8;++e) dst[e] = (f[e]-mean)*rstd*g[e] + bbv[e];
    }
  }
  __syncthreads();
}

// ---------------- full forward for one batch element ----------------
template<int BF> __device__ void run_all(float* sm,
    const void* x, const void* st, const void* cw4, const void* cw3, const void* cw2,
    const void* cw1, const void* cb, const void* qw, const void* qb, const void* ow,
    const void* ob, const void* ffw, const void* ang, const void* anb, const void* gk,
    const void* grr, const void* gbb, const void* sg, const void* sb2,
    void* outp, float* bypass)
{
  const int tid = threadIdx.x;
  const int b   = blockIdx.x;

  for (int o=tid; o<4096; o+=TPB){ int p=o>>6, d=o&63;
    sm[O_LAST+o] = ldf<BF>(x, (long)b*5120 + p*80 + d); }
  for (int o=tid; o<1024; o+=TPB){ int c=o>>6, j=o&63;
    sm[O_MST+o] = ldf<BF>(st, (long)b*1024 + o) + ldf<BF>(x, (long)b*5120 + j*80 + 64 + c); }
  __syncthreads();

  for (int li=0; li<8; ++li){
    //================= Stage A: 3D convs -> cc in O_BIG =================
    {
      const float* LAST = sm + O_LAST;
      { int prt = tid>>4, q4 = tid&15, n0 = q4*4;
        float a0=0,a1=0,a2=0,a3=0;
        for (int pp=prt*2; pp<prt*2+2; ++pp){
          long wb = ((long)(li*64+pp))*4096 + n0;
          const float* Xr = LAST + pp*64;
          #pragma unroll 8
          for (int d=0; d<64; ++d){ float w0,w1,w2,w3; ldw4<BF>(cw4, wb+(long)d*64, w0,w1,w2,w3);
            float xv=Xr[d]; a0+=xv*w0; a1+=xv*w1; a2+=xv*w2; a3+=xv*w3; } }
        float* dst = sm + C4P + prt*64 + n0; dst[0]=a0; dst[1]=a1; dst[2]=a2; dst[3]=a3; }
      if (tid < 432){
        int r = tid>>4, q4 = tid&15, n0 = q4*4;
        int oz = r/9, rem = r-oz*9, oy = rem/3, ox = rem-oy*3;
        float a0,a1,a2,a3; ldw4<BF>(cb, (long)(li*4+2)*64+n0, a0,a1,a2,a3);
        #pragma unroll
        for (int kz=0; kz<2; ++kz)
        #pragma unroll
        for (int ky=0; ky<2; ++ky)
        #pragma unroll
        for (int kx=0; kx<2; ++kx){
          int pos = (oz+kz)*16 + (oy+ky)*4 + (ox+kx);
          long wb = ((long)(li*8 + kz*4+ky*2+kx))*4096 + n0;
          const float* Xr = LAST + pos*64;
          #pragma unroll 8
          for (int d=0; d<64; ++d){ float w0,w1,w2,w3; ldw4<BF>(cw2, wb+(long)d*64, w0,w1,w2,w3);
            float xv=Xr[d]; a0+=xv*w0; a1+=xv*w1; a2+=xv*w2; a3+=xv*w3; } }
        float* dst = sm + O_BIG + (9+r)*65 + n0; dst[0]=a0; dst[1]=a1; dst[2]=a2; dst[3]=a3; }
      for (int tk=tid; tk<1024; tk+=TPB){
        int r = tk>>4, n0 = (tk&15)*4;
        float a0,a1,a2,a3; ldw4<BF>(cb, (long)(li*4+3)*64+n0, a0,a1,a2,a3);
        long wb = (long)li*4096 + n0;
        const float* Xr = LAST + r*64;
        #pragma unroll 8
        for (int d=0; d<64; ++d){ float w0,w1,w2,w3; ldw4<BF>(cw1, wb+(long)d*64, w0,w1,w2,w3);
          float xv=Xr[d]; a0+=xv*w0; a1+=xv*w1; a2+=xv*w2; a3+=xv*w3; }
        float* dst = sm + O_BIG + (36+r)*65 + n0; dst[0]=a0; dst[1]=a1; dst[2]=a2; dst[3]=a3; }
      __syncthreads();
      if (tid < 64){
        float a = ldf<BF>(cb, (long)(li*4+0)*64 + tid);
        for (int p2=0; p2<32; ++p2) a += sm[C4P + p2*64 + tid];
        sm[O_BIG + tid] = a; }
      { int r = tid>>6, q4 = (tid>>2)&15, kpart = tid&3, n0 = q4*4;
        int oz = (r>>2)&1, oy = (r>>1)&1, ox = r&1;
        float a0=0,a1=0,a2=0,a3=0;
        for (int kp=kpart; kp<27; kp+=4){
          int kz = kp/9, kr = kp-kz*9, ky = kr/3, kx = kr-ky*3;
          int pos = (oz+kz)*16 + (oy+ky)*4 + (ox+kx);
          long wb = ((long)(li*27+kp))*4096 + n0;
          const float* Xr = LAST + pos*64;
          #pragma unroll 8
          for (int d=0; d<64; ++d){ float w0,w1,w2,w3; ldw4<BF>(cw3, wb+(long)d*64, w0,w1,w2,w3);
            float xv=Xr[d]; a0+=xv*w0; a1+=xv*w1; a2+=xv*w2; a3+=xv*w3; } }
        float* dst = sm + C3P + (r*16+q4)*16 + kpart*4;
        dst[0]=a0; dst[1]=a1; dst[2]=a2; dst[3]=a3; }
      __syncthreads();
      if (tid < 128){
        int t3 = tid, r = t3>>4, n0 = (t3&15)*4;
        float b0,b1,b2,b3; ldw4<BF>(cb, (long)(li*4+1)*64+n0, b0,b1,b2,b3);
        const float* pp = sm + C3P + t3*16;
        float* dst = sm + O_BIG + (1+r)*65 + n0;
        dst[0] = b0 + pp[0] + pp[4] + pp[8]  + pp[12];
        dst[1] = b1 + pp[1] + pp[5] + pp[9]  + pp[13];
        dst[2] = b2 + pp[2] + pp[6] + pp[10] + pp[14];
        dst[3] = b3 + pp[3] + pp[7] + pp[11] + pp[15]; }
      __syncthreads();
    }

    //================= Stage B: MHA0 + ff + LN -> d0 (f32, O_D0T) =================
    mha_ff_ln<BF>(sm, li, 0, 100, qw, qb, ow, ob, ffw, ang, anb);

    //================= Stage D: bidirectional GRU (full f32) -> ap in O_BIG ======
    {
      float rza[64], rra[64], rha[64];   // rec threads: R columns (f32, regs)
      float kc[64];                       // xg threads: K column (f32, regs)
      float hmy=0, brz=0, brr=0, brh=0, bi=0;
      int hdir = 0, hgg = 0;
      const int dirw = (tid>>6)&1, jl = tid&63;
      if (tid < 128){
        long rb = (long)((li*2+dirw)*64)*192;
        #pragma unroll
        for (int q=0; q<64; ++q){
          rza[q] = ldf<BF>(grr, rb + (long)q*192 +      jl);
          rra[q] = ldf<BF>(grr, rb + (long)q*192 +  64+jl);
          rha[q] = ldf<BF>(grr, rb + (long)q*192 + 128+jl);
        }
        long bb = (long)((li*2+dirw)*2+1)*192;
        brz = ldf<BF>(gbb, bb+jl); brr = ldf<BF>(gbb, bb+64+jl); brh = ldf<BF>(gbb, bb+128+jl);
        hmy = sm[O_MST + (li*2+dirw)*64 + jl];
        sm[HBUF + dirw*64 + jl] = hmy;
      } else {
        int c = tid-128; hdir = (c>=192); hgg = c - hdir*192;
        long kb = (long)((li*2+hdir)*64)*192;
        #pragma unroll
        for (int q=0; q<64; ++q) kc[q] = ldf<BF>(gk, kb + (long)q*192 + hgg);
        bi = ldf<BF>(gbb, (long)((li*2+hdir)*2)*192 + hgg);
      }
      __syncthreads();
      if (tid >= 128){ int c = tid-128;
        for (int pre=0; pre<2; ++pre){
          int xi = hdir ? (63-pre) : pre;
          const float* XP = sm + O_D0T + xi*65;
          float a = bi;
          #pragma unroll
          for (int q=0; q<64; ++q) a += XP[q]*kc[q];
          sm[XGR + pre*384 + c] = a; } }
      __syncthreads();
      for (int t=0; t<64; ++t){
        if (tid < 128){
          const float* ring = sm + XGR + (t&3)*384 + dirw*192;
          float xz = ring[jl], xr = ring[64+jl], xh = ring[128+jl];
          float az = brz, ar = brr, hh = brh;
          const float* HP = sm + HBUF + dirw*64;
          #pragma unroll
          for (int q=0; q<64; ++q){ float hv = HP[q];
            az += hv*rza[q]; ar += hv*rra[q]; hh += hv*rha[q]; }
          az += xz; ar += xr;
          float z  = 1.f/(1.f + __expf(-az));
          float rt = 1.f/(1.f + __expf(-ar));
          float ca = xh + rt*hh; ca = fminf(fmaxf(ca, -15.f), 15.f);
          float e2 = __expf(2.f*ca);
          float cand = (e2-1.f)/(e2+1.f);
          float hn = z*hmy + (1.f-z)*cand;
          hmy = hn;
          sm[O_BIG + (dirw*64+jl)*65 + t] = hn;
          sm[HBUF + dirw*64 + jl] = hn;
        } else if (t+2 < 64){
          int c = tid-128, pre = t+2;
          int xi = hdir ? (63-pre) : pre;
          const float* XP = sm + O_D0T + xi*65;
          float a = bi;
          #pragma unroll
          for (int q=0; q<64; ++q) a += XP[q]*kc[q];
          sm[XGR + ((t+2)&3)*384 + c] = a;
        }
        __syncthreads();
      }
      if (tid < 128) sm[O_MST + (li*2+dirw)*64 + jl] = hmy;
      __syncthreads();
    }

    //================= Stage E: MHA1 + ff + LN -> d1 in O_LAST =================
    mha_ff_ln<BF>(sm, li, 1, 128, qw, qb, ow, ob, ffw, ang, anb);

    //================= Stage G: bypass + skip LNs =================
    if ((li&1) == 0){
      float* bp = bypass + ((long)b*4 + (li>>1))*4096;
      for (int o=tid; o<4096; o+=TPB) bp[o] = sm[O_LAST+o];
    }
    __syncthreads();
    { int jmp = 1, sidx = 0;
      while (((li+1) % jmp) == 0){
        int src = li - jmp + 1;
        { int r = tid>>3, prt = tid&7;
          const float* L = sm + O_LAST + r*64 + prt*8;
          const float* bpr = bypass + ((long)b*4 + (src>>1))*4096 + r*64 + prt*8;
          float f[8]; float s1=0, s2=0;
          #pragma unroll
          for (int e=0; e<8; ++e){
            float av = (src==li) ? L[e] : bpr[e];
            float fv = av + L[e]; f[e]=fv; s1+=fv; s2+=fv*fv; }
          s1 += __shfl_xor(s1,4); s1 += __shfl_xor(s1,2); s1 += __shfl_xor(s1,1);
          s2 += __shfl_xor(s2,4); s2 += __shfl_xor(s2,2); s2 += __shfl_xor(s2,1);
          float mean = s1*0.015625f, var = s2*0.015625f - mean*mean;
          float rstd = rsqrtf(var + 1e-3f);
          long gb2 = (long)(li*4 + sidx)*64 + prt*8;
          float g[8], bbv[8];
          ldw4<BF>(sg,  gb2,   g[0],g[1],g[2],g[3]);     ldw4<BF>(sg,  gb2+4, g[4],g[5],g[6],g[7]);
          ldw4<BF>(sb2, gb2,   bbv[0],bbv[1],bbv[2],bbv[3]); ldw4<BF>(sb2, gb2+4, bbv[4],bbv[5],bbv[6],bbv[7]);
          float* W = sm + O_LAST + r*64 + prt*8;
          #pragma unroll
          for (int e=0; e<8; ++e) W[e] = (f[e]-mean)*rstd*g[e] + bbv[e];
        }
        jmp *= 2; ++sidx;
        __syncthreads();
      } }
  } // layers

  for (int o=tid; o<5120; o+=TPB){
    int p = o/80, d = o - p*80;
    float v = (d<64) ? sm[O_LAST + p*64 + d] : sm[O_MST + (d-64)*64 + p];
    stf<BF>(outp, (long)b*5120 + o, v);
  }
  for (int o=tid; o<1024; o+=TPB)
    stf<BF>(outp, (long)256*5120 + (long)b*1024 + o, sm[O_MST+o]);
}

// dtype sniffer: an_g ~= 1.0 +- 0.02. If stored bf16, both u16 halves of each
// dword decode to ~1.0; if f32, the low half is random mantissa bits.
__global__ void detect_dtype(const void* ang, int* flag){
  if (threadIdx.x == 0 && blockIdx.x == 0){
    const unsigned* w = (const unsigned*)ang;
    int good = 0;
    for (int k=0; k<64; ++k){
      unsigned u = w[k];
      float lo = __builtin_bit_cast(float, (u & 0xFFFFu) << 16);
      float hi = __builtin_bit_cast(float, u & 0xFFFF0000u);
      if (lo > 0.7f && lo < 1.4f && hi > 0.7f && hi < 1.4f) ++good;
    }
    *flag = (good >= 48) ? 1 : 0;
  }
}

__global__ void __launch_bounds__(TPB, 2) converter_kernel(
    const void* x, const void* st, const void* cw4, const void* cw3, const void* cw2,
    const void* cw1, const void* cb, const void* qw, const void* qb, const void* ow,
    const void* ob, const void* ffw, const void* ang, const void* anb, const void* gk,
    const void* grr, const void* gbb, const void* sg, const void* sb2,
    const int* flagp, void* outp, float* bypass)
{
  extern __shared__ float sm[];
  if (*flagp)
    run_all<1>(sm, x, st, cw4, cw3, cw2, cw1, cb, qw, qb, ow, ob, ffw, ang, anb,
               gk, grr, gbb, sg, sb2, outp, bypass);
  else
    run_all<0>(sm, x, st, cw4, cw3, cw2, cw1, cb, qw, qb, ow, ob, ffw, ang, anb,
               gk, grr, gbb, sg, sb2, outp, bypass);
}

extern "C" void kernel_launch(void* const* d_in, const int* in_sizes, int n_in,
                              void* d_out, int out_size, void* d_ws, size_t ws_size,
                              hipStream_t stream) {
  (void)in_sizes; (void)n_in; (void)out_size; (void)ws_size;
  int*   flag   = (int*)d_ws;
  float* bypass = (float*)((char*)d_ws + 256);   // 256*4*4096 f32 = 16.8 MB

  hipFuncSetAttribute(reinterpret_cast<const void*>(converter_kernel),
                      hipFuncAttributeMaxDynamicSharedMemorySize, SMF*4);

  detect_dtype<<<1, 64, 0, stream>>>(d_in[12], flag);
  converter_kernel<<<256, TPB, SMF*4, stream>>>(
      d_in[0], d_in[1], d_in[2], d_in[3], d_in[4], d_in[5], d_in[6], d_in[7],
      d_in[8], d_in[9], d_in[10], d_in[11], d_in[12], d_in[13], d_in[14],
      d_in[15], d_in[16], d_in[17], d_in[18], flag, d_out, bypass);
}

// Round 3
// 4475.443 us; speedup vs baseline: 1.8263x; 1.8263x over previous
//
#include <hip/hip_runtime.h>
#include <hip/hip_bf16.h>

// One block per batch element (256 blocks x 512 threads). All activations in
// dynamic LDS (~152KB -> 1 block/CU). Full f32 math (R2 numerics kept).
// R3: latency-oriented restructure: LDS-staged conv weight slices (dbuf),
// float4-batched LDS reads everywhere, 2-pass softmax (fewer barriers),
// GRU hh-weights in LDS (reg pressure), z/r weights in regs.

#define TPB 512

// ---- LDS layout (float slots) ----
constexpr int O_LAST = 0;            // 4096 : last / d1   [p*64+d]
constexpr int O_D0T  = 4096;         // 4352 : d0 transposed [ch*68 + pos]
constexpr int O_BIG  = 8448;         // 8704 : cc (100x64) / ap (128x64), row stride 68
constexpr int O_SCR  = 17152;        // 7424 : stage-disjoint scratch
constexpr int O_MST  = 24576;        // 1024 : mstate / GRU states [(i*2+dir)*64+j]
constexpr int O_RED  = 25600;        // 128  : small reductions
constexpr int XTRA   = 25728;        // 12288: staged weights (conv dbuf / mhaW / gru hh)
constexpr int SMF    = 38016;        // 152,064 bytes

// O_SCR sub-regions (stage-disjoint):
constexpr int C4P   = O_SCR;         // conv: c4 partials (4096)
constexpr int C3P   = O_SCR + 4096;  // conv: c3 partials (2048)
constexpr int QKVS  = O_SCR;         // mha: q/k/v slices, m*1536 + s*12 + c (4608)
constexpr int LINVo = O_SCR + 4608;  // mha: 1/rowsum (128)
constexpr int PCOLo = O_SCR + 4736;  // mha: colsum partials 4x128 (512)
constexpr int XGR   = O_SCR;         // gru: xg ring, 4 slots x 384 (1536)
constexpr int HBUF  = O_SCR + 1536;  // gru: h state f32, 2 dirs x 64 (128)

// O_RED sub-slots:
constexpr int WOS  = O_RED;          // 64
constexpr int BOS  = O_RED + 64;
constexpr int ACCS = O_RED + 65;
constexpr int SVV  = O_RED + 66;     // 8
constexpr int HSW  = O_RED + 74;     // 8
constexpr int HSV  = O_RED + 82;

__device__ __forceinline__ float b2f(unsigned s){ return __builtin_bit_cast(float, s<<16); }

template<int BF> __device__ __forceinline__ float ldf(const void* p, long i){
  if (BF){ unsigned v = ((unsigned)((const unsigned short*)p)[i]) << 16;
           return __builtin_bit_cast(float, v); }
  return ((const float*)p)[i];
}
template<int BF> __device__ __forceinline__ void ldw4(const void* p, long i,
                                                      float&a,float&b,float&c,float&d){
  if (BF){ uint2 u = *(const uint2*)((const unsigned short*)p + i);
    a=b2f(u.x&0xffffu); b=b2f(u.x>>16); c=b2f(u.y&0xffffu); d=b2f(u.y>>16);
  } else { float4 f = *(const float4*)((const float*)p + i); a=f.x;b=f.y;c=f.z;d=f.w; }
}
template<int BF> __device__ __forceinline__ void ld8(const void* p, long i, float* v){
  if (BF){
    uint4 u = *(const uint4*)((const unsigned short*)p + i);
    v[0]=b2f(u.x&0xffffu); v[1]=b2f(u.x>>16);
    v[2]=b2f(u.y&0xffffu); v[3]=b2f(u.y>>16);
    v[4]=b2f(u.z&0xffffu); v[5]=b2f(u.z>>16);
    v[6]=b2f(u.w&0xffffu); v[7]=b2f(u.w>>16);
  } else {
    float4 a=*(const float4*)((const float*)p+i), b=*(const float4*)((const float*)p+i+4);
    v[0]=a.x;v[1]=a.y;v[2]=a.z;v[3]=a.w;v[4]=b.x;v[5]=b.y;v[6]=b.z;v[7]=b.w;
  }
}
template<int BF> __device__ __forceinline__ void stf(void* p, long i, float v){
  if (BF){ unsigned u=__builtin_bit_cast(unsigned,v);
           u += 0x7FFFu + ((u>>16)&1u);
           ((unsigned short*)p)[i]=(unsigned short)(u>>16); }
  else ((float*)p)[i]=v;
}
__device__ __forceinline__ float dot8(float4 a0, float4 a1, float4 b0, float4 b1){
  return a0.x*b0.x+a0.y*b0.y+a0.z*b0.z+a0.w*b0.w
       + a1.x*b1.x+a1.y*b1.y+a1.z*b1.z+a1.w*b1.w;
}

// cooperative stage of one 64x64 weight slice (flat 4096 elems) into LDS
template<int BF> __device__ __forceinline__ void stage_slice(float* sm, int dst,
                                                             const void* w, long base){
  int e0 = threadIdx.x * 8;
  float v[8]; ld8<BF>(w, base + e0, v);
  float* dp = sm + dst + e0;
  *(float4*)dp     = make_float4(v[0],v[1],v[2],v[3]);
  *(float4*)(dp+4) = make_float4(v[4],v[5],v[6],v[7]);
}

// ---------------- MHA (collapsed) + ff + LN ----------------
template<int BF> __device__ void mha_ff_ln(float* sm, int li, int jj, int S,
    const void* qw, const void* qb, const void* ow, const void* ob,
    const void* ffw, const void* ang, const void* anb)
{
  const int tid = threadIdx.x;
  const int b2  = li*2 + jj;
  const float SC = 0.35355339059327378f;

  // stage full Wqkv (3x64x64) into XTRA (flat per m)
  #pragma unroll
  for (int m=0; m<3; ++m){
    int rem = tid*8;
    float v[8]; ld8<BF>(qw, ((long)(b2*3+m))*4096 + rem, v);
    float* dp = sm + XTRA + m*4096 + rem;
    *(float4*)dp     = make_float4(v[0],v[1],v[2],v[3]);
    *(float4*)(dp+4) = make_float4(v[4],v[5],v[6],v[7]);
  }
  if (tid < 64){
    float s = 0; long wb = ((long)b2*64 + tid)*64;
    #pragma unroll 4
    for (int d=0; d<64; d+=4){ float a0,a1,a2,a3; ldw4<BF>(ow, wb+d, a0,a1,a2,a3); s += a0+a1+a2+a3; }
    sm[WOS+tid] = s;
  } else if (tid == 64){
    float s = 0; long bb = (long)b2*64;
    for (int d=0; d<64; ++d) s += ldf<BF>(ob, bb+d);
    sm[BOS] = s;
  } else if (tid == 65){ sm[ACCS] = 0.f; }
  __syncthreads();

  for (int h=0; h<8; ++h){
    // fold previous head's sv into ACCS (reads SVV written before last barrier)
    if (tid == 0 && h > 0){
      float a = sm[ACCS];
      #pragma unroll
      for (int c=0;c<8;++c) a += sm[SVV+c]*sm[WOS + (h-1)*8 + c];
      sm[ACCS] = a;
    }
    // ---- qkv GEMV for head h ----
    { int S2 = S*2, tot = 3*S2;
      for (int tk=tid; tk<tot; tk+=TPB){
        int m = (tk>=2*S2)?2:((tk>=S2)?1:0);
        int rem = tk - m*S2, s = rem>>1, c0 = (rem&1)*4;
        float a0,a1,a2,a3; ldw4<BF>(qb, (long)(b2*3+m)*64 + h*8 + c0, a0,a1,a2,a3);
        const float* Xr = sm + O_BIG + s*68;
        const float* Wb = sm + XTRA + m*4096 + h*8 + c0;
        #pragma unroll 4
        for (int dd=0; dd<64; dd+=4){
          float4 xv = *(const float4*)(Xr + dd);
          float4 w0 = *(const float4*)(Wb + (dd+0)*64);
          float4 w1 = *(const float4*)(Wb + (dd+1)*64);
          float4 w2 = *(const float4*)(Wb + (dd+2)*64);
          float4 w3 = *(const float4*)(Wb + (dd+3)*64);
          a0 += xv.x*w0.x + xv.y*w1.x + xv.z*w2.x + xv.w*w3.x;
          a1 += xv.x*w0.y + xv.y*w1.y + xv.z*w2.y + xv.w*w3.y;
          a2 += xv.x*w0.z + xv.y*w1.z + xv.z*w2.z + xv.w*w3.z;
          a3 += xv.x*w0.w + xv.y*w1.w + xv.z*w2.w + xv.w*w3.w;
        }
        *(float4*)(sm + QKVS + m*1536 + s*12 + c0) = make_float4(a0,a1,a2,a3);
      } }
    __syncthreads();
    // ---- pass1: per-row sums (wave-local), LINV = 1/rowsum ----
    { int w = tid>>6, l = tid&63;
      const float* Kp = sm + QKVS + 1536;
      float4 ka0 = *(const float4*)(Kp + l*12), ka1 = *(const float4*)(Kp + l*12 + 4);
      bool hasb = (l+64) < S;
      float4 kb0, kb1;
      if (hasb){ kb0 = *(const float4*)(Kp + (l+64)*12); kb1 = *(const float4*)(Kp + (l+64)*12 + 4); }
      for (int q=w; q<S; q+=8){
        float4 q0 = *(const float4*)(sm + QKVS + q*12);
        float4 q1 = *(const float4*)(sm + QKVS + q*12 + 4);
        float e = __expf(dot8(q0,q1,ka0,ka1)*SC);
        if (hasb) e += __expf(dot8(q0,q1,kb0,kb1)*SC);
        e += __shfl_xor(e,32); e += __shfl_xor(e,16); e += __shfl_xor(e,8);
        e += __shfl_xor(e,4);  e += __shfl_xor(e,2);  e += __shfl_xor(e,1);
        if (l==0) sm[LINVo+q] = 1.f/e;
      } }
    __syncthreads();
    // ---- pass2: colsum via recompute ----
    { int ss = tid&127, qg = tid>>7;
      float acc = 0.f;
      if (ss < S){
        const float* Kp = sm + QKVS + 1536;
        float4 k0 = *(const float4*)(Kp + ss*12), k1 = *(const float4*)(Kp + ss*12 + 4);
        for (int q=qg; q<S; q+=4){
          float4 q0 = *(const float4*)(sm + QKVS + q*12);
          float4 q1 = *(const float4*)(sm + QKVS + q*12 + 4);
          acc += __expf(dot8(q0,q1,k0,k1)*SC) * sm[LINVo+q];
        }
      }
      sm[PCOLo + qg*128 + ss] = acc; }
    __syncthreads();
    // ---- sv[c] = sum_s colsum[s]*v[s,c] ----
    { int c = tid>>6, l = tid&63;
      const float* VH = sm + QKVS + 3072;
      float cs0 = sm[PCOLo+l] + sm[PCOLo+128+l] + sm[PCOLo+256+l] + sm[PCOLo+384+l];
      float pv = cs0 * VH[l*12 + c];
      if (l+64 < S){
        float cs1 = sm[PCOLo+l+64] + sm[PCOLo+128+l+64] + sm[PCOLo+256+l+64] + sm[PCOLo+384+l+64];
        pv += cs1 * VH[(l+64)*12 + c];
      }
      pv += __shfl_xor(pv,32); pv += __shfl_xor(pv,16); pv += __shfl_xor(pv,8);
      pv += __shfl_xor(pv,4);  pv += __shfl_xor(pv,2);  pv += __shfl_xor(pv,1);
      if (l==0) sm[SVV+c] = pv; }
    __syncthreads();
  }
  if (tid == 0){
    float a = sm[ACCS];
    #pragma unroll
    for (int c=0;c<8;++c) a += sm[SVV+c]*sm[WOS + 7*8 + c];
    sm[ACCS] = a;
  }
  __syncthreads();

  const float s_scalar = sm[ACCS] + (float)S*sm[BOS];

  // hs = sum relu(s*ffw0)
  float part = 0;
  { long fb = (long)(b2*2)*4096;
    for (int q4=tid; q4<1024; q4+=TPB){
      float a0,a1,a2,a3; ldw4<BF>(ffw, fb + (long)q4*4, a0,a1,a2,a3);
      part += fmaxf(s_scalar*a0,0.f)+fmaxf(s_scalar*a1,0.f)
            + fmaxf(s_scalar*a2,0.f)+fmaxf(s_scalar*a3,0.f); } }
  part += __shfl_xor(part,32); part += __shfl_xor(part,16); part += __shfl_xor(part,8);
  part += __shfl_xor(part,4);  part += __shfl_xor(part,2);  part += __shfl_xor(part,1);
  if ((tid&63)==0) sm[HSW + (tid>>6)] = part;
  __syncthreads();
  if (tid == 0){ float v=0; for (int w=0;w<8;++w) v += sm[HSW+w]; sm[HSV]=v; }
  __syncthreads();
  const float hs = sm[HSV];

  // LN rows: 64 rows x 8 threads
  { int r = tid>>3, prt = tid&7;
    long f1b = (long)(b2*2+1)*4096 + r*64 + prt*8;
    float rs[8];
    if (jj == 0){
      const float4* R = (const float4*)(sm + O_LAST + r*64 + prt*8);
      float4 r0 = R[0], r1 = R[1];
      rs[0]=r0.x; rs[1]=r0.y; rs[2]=r0.z; rs[3]=r0.w;
      rs[4]=r1.x; rs[5]=r1.y; rs[6]=r1.z; rs[7]=r1.w;
    } else {
      #pragma unroll
      for (int e=0;e<8;++e) rs[e] = sm[O_D0T + (prt*8+e)*68 + r];
    }
    float w[8];
    ldw4<BF>(ffw, f1b,   w[0],w[1],w[2],w[3]);
    ldw4<BF>(ffw, f1b+4, w[4],w[5],w[6],w[7]);
    float f[8]; float s1=0, s2=0;
    #pragma unroll
    for (int e=0;e<8;++e){ float fv = hs*w[e] + rs[e]; f[e]=fv; s1+=fv; s2+=fv*fv; }
    s1 += __shfl_xor(s1,4); s1 += __shfl_xor(s1,2); s1 += __shfl_xor(s1,1);
    s2 += __shfl_xor(s2,4); s2 += __shfl_xor(s2,2); s2 += __shfl_xor(s2,1);
    float mean = s1*0.015625f, var = s2*0.015625f - mean*mean;
    float rstd = rsqrtf(var + 1e-3f);
    long gb2 = (long)b2*64 + prt*8;
    float g[8], bbv[8];
    ldw4<BF>(ang, gb2,   g[0],g[1],g[2],g[3]);   ldw4<BF>(ang, gb2+4, g[4],g[5],g[6],g[7]);
    ldw4<BF>(anb, gb2,   bbv[0],bbv[1],bbv[2],bbv[3]); ldw4<BF>(anb, gb2+4, bbv[4],bbv[5],bbv[6],bbv[7]);
    if (jj == 0){
      #pragma unroll
      for (int e=0;e<8;++e) sm[O_D0T + (prt*8+e)*68 + r] = (f[e]-mean)*rstd*g[e] + bbv[e];
    } else {
      float* dst = sm + O_LAST + r*64 + prt*8;
      #pragma unroll
      for (int e=0;e<8;++e) dst[e] = (f[e]-mean)*rstd*g[e] + bbv[e];
    }
  }
  __syncthreads();
}

// ---------------- full forward for one batch element ----------------
template<int BF> __device__ void run_all(float* sm,
    const void* x, const void* st, const void* cw4, const void* cw3, const void* cw2,
    const void* cw1, const void* cb, const void* qw, const void* qb, const void* ow,
    const void* ob, const void* ffw, const void* ang, const void* anb, const void* gk,
    const void* grr, const void* gbb, const void* sg, const void* sb2,
    void* outp, float* bypass)
{
  const int tid = threadIdx.x;
  const int b   = blockIdx.x;

  for (int o=tid; o<4096; o+=TPB){ int p=o>>6, d=o&63;
    sm[O_LAST+o] = ldf<BF>(x, (long)b*5120 + p*80 + d); }
  for (int o=tid; o<1024; o+=TPB){ int c=o>>6, j=o&63;
    sm[O_MST+o] = ldf<BF>(st, (long)b*1024 + o) + ldf<BF>(x, (long)b*5120 + j*80 + 64 + c); }
  __syncthreads();

  for (int li=0; li<8; ++li){
    //================= Stage A: 3D convs -> cc in O_BIG (stride 68) =============
    {
      // ---- c4 partials: thread (prt=pos, g=octet) -> C4P[prt*64+n]
      { int prt = tid>>3, g = tid&7, n0 = g*8;
        const float* Xr = sm + O_LAST + prt*64;
        float a[8];
        #pragma unroll
        for (int e=0;e<8;++e) a[e]=0.f;
        long wb = ((long)(li*64+prt))*4096 + n0;
        #pragma unroll 2
        for (int dd=0; dd<64; dd+=4){
          float4 xv = *(const float4*)(Xr + dd);
          float xs[4] = {xv.x, xv.y, xv.z, xv.w};
          float w[4][8];
          #pragma unroll
          for (int k=0;k<4;++k) ld8<BF>(cw4, wb + (long)(dd+k)*64, w[k]);
          #pragma unroll
          for (int k=0;k<4;++k)
            #pragma unroll
            for (int e=0;e<8;++e) a[e] += xs[k]*w[k][e];
        }
        float* dst = sm + C4P + prt*64 + n0;
        *(float4*)dst     = make_float4(a[0],a[1],a[2],a[3]);
        *(float4*)(dst+4) = make_float4(a[4],a[5],a[6],a[7]);
      }
      // ---- stage c1 slice
      stage_slice<BF>(sm, XTRA, cw1, (long)li*4096);
      __syncthreads();
      // ---- c1 compute (buf0) + stage c2 s0 (buf1)
      {
        stage_slice<BF>(sm, XTRA+4096, cw2, (long)(li*8+0)*4096);
        int r = tid>>3, g = tid&7, n0 = g*8;
        float a[8];
        ldw4<BF>(cb, (long)(li*4+3)*64 + n0,     a[0],a[1],a[2],a[3]);
        ldw4<BF>(cb, (long)(li*4+3)*64 + n0 + 4, a[4],a[5],a[6],a[7]);
        const float* Xr = sm + O_LAST + r*64;
        const float* W  = sm + XTRA + n0;
        #pragma unroll 2
        for (int dd=0; dd<64; dd+=4){
          float4 xv = *(const float4*)(Xr + dd);
          float xs[4] = {xv.x, xv.y, xv.z, xv.w};
          #pragma unroll
          for (int k=0;k<4;++k){
            float4 wA = *(const float4*)(W + (dd+k)*64);
            float4 wB = *(const float4*)(W + (dd+k)*64 + 4);
            a[0]+=xs[k]*wA.x; a[1]+=xs[k]*wA.y; a[2]+=xs[k]*wA.z; a[3]+=xs[k]*wA.w;
            a[4]+=xs[k]*wB.x; a[5]+=xs[k]*wB.y; a[6]+=xs[k]*wB.z; a[7]+=xs[k]*wB.w;
          }
        }
        float* dst = sm + O_BIG + (36+r)*68 + n0;
        *(float4*)dst     = make_float4(a[0],a[1],a[2],a[3]);
        *(float4*)(dst+4) = make_float4(a[4],a[5],a[6],a[7]);
      }
      __syncthreads();
      // ---- c2: 8 slices, dbuf; acc in regs across slices
      {
        float a[4] = {0,0,0,0};
        int r=0, n0=0;
        bool act = tid < 432;
        if (act){
          r = tid>>4; n0 = (tid&15)*4;
          ldw4<BF>(cb, (long)(li*4+2)*64 + n0, a[0],a[1],a[2],a[3]);
        }
        for (int s=0; s<8; ++s){
          if (s<7) stage_slice<BF>(sm, XTRA + (s&1)*4096, cw2, (long)(li*8+s+1)*4096);
          if (act){
            int kz=(s>>2)&1, ky=(s>>1)&1, kx=s&1;
            int oz=r/9, remm=r-oz*9, oy=remm/3, ox=remm-oy*3;
            int pos=(oz+kz)*16+(oy+ky)*4+(ox+kx);
            const float* Xr = sm + O_LAST + pos*64;
            const float* W  = sm + XTRA + ((s+1)&1)*4096 + n0;
            #pragma unroll 4
            for (int dd=0; dd<64; dd+=4){
              float4 xv = *(const float4*)(Xr + dd);
              float xs[4] = {xv.x, xv.y, xv.z, xv.w};
              #pragma unroll
              for (int k=0;k<4;++k){
                float4 w = *(const float4*)(W + (dd+k)*64);
                a[0]+=xs[k]*w.x; a[1]+=xs[k]*w.y; a[2]+=xs[k]*w.z; a[3]+=xs[k]*w.w;
              }
            }
          }
          __syncthreads();
        }
        if (act) *(float4*)(sm + O_BIG + (9+r)*68 + n0) = make_float4(a[0],a[1],a[2],a[3]);
      }
      // ---- c3: 27 slices, dbuf; d-split x4; acc in regs
      stage_slice<BF>(sm, XTRA, cw3, (long)(li*27+0)*4096);
      __syncthreads();
      {
        float a[4] = {0,0,0,0};
        int r3 = tid>>6, q43 = (tid>>2)&15, dq = tid&3, n03 = q43*4;
        int oz3=(r3>>2)&1, oy3=(r3>>1)&1, ox3=r3&1;
        for (int kp=0; kp<27; ++kp){
          if (kp<26) stage_slice<BF>(sm, XTRA + ((kp+1)&1)*4096, cw3, (long)(li*27+kp+1)*4096);
          int kz=kp/9, kr=kp-kz*9, ky=kr/3, kx=kr-ky*3;
          int pos=(oz3+kz)*16+(oy3+ky)*4+(ox3+kx);
          const float* Xr = sm + O_LAST + pos*64 + dq*16;
          const float* W  = sm + XTRA + (kp&1)*4096 + dq*16*64 + n03;
          #pragma unroll
          for (int dd=0; dd<16; dd+=4){
            float4 xv = *(const float4*)(Xr + dd);
            float xs[4] = {xv.x, xv.y, xv.z, xv.w};
            #pragma unroll
            for (int k=0;k<4;++k){
              float4 w = *(const float4*)(W + (dd+k)*64);
              a[0]+=xs[k]*w.x; a[1]+=xs[k]*w.y; a[2]+=xs[k]*w.z; a[3]+=xs[k]*w.w;
            }
          }
          __syncthreads();
        }
        float* dst = sm + C3P + ((r3*16+q43)*16 + dq*4);
        dst[0]=a[0]; dst[1]=a[1]; dst[2]=a[2]; dst[3]=a[3];
      }
      __syncthreads();
      // ---- reduces: c3 rows (tid<128), c4 row (tid 256..320)
      if (tid < 128){
        int r = tid>>4, n0 = (tid&15)*4;
        float b0,b1,b2,b3; ldw4<BF>(cb, (long)(li*4+1)*64+n0, b0,b1,b2,b3);
        const float* pp = sm + C3P + tid*16;
        float* dst = sm + O_BIG + (1+r)*68 + n0;
        dst[0] = b0 + pp[0] + pp[4] + pp[8]  + pp[12];
        dst[1] = b1 + pp[1] + pp[5] + pp[9]  + pp[13];
        dst[2] = b2 + pp[2] + pp[6] + pp[10] + pp[14];
        dst[3] = b3 + pp[3] + pp[7] + pp[11] + pp[15];
      } else if (tid >= 256 && tid < 320){
        int n = tid - 256;
        float a = ldf<BF>(cb, (long)(li*4+0)*64 + n);
        for (int p2=0; p2<64; ++p2) a += sm[C4P + p2*64 + n];
        sm[O_BIG + n] = a;
      }
      __syncthreads();
    }

    //================= Stage B: MHA0 + ff + LN -> d0 (O_D0T) =================
    mha_ff_ln<BF>(sm, li, 0, 100, qw, qb, ow, ob, ffw, ang, anb);

    //================= Stage D: bidirectional GRU -> ap in O_BIG =================
    {
      // stage hh-gate recurrent weights into XTRA: [dir][k=q>>2][j][e=q&3]
      { int e0 = tid*16; int dir = e0>>12; int rem = e0&4095; int q = rem>>6; int j0 = rem&63;
        long sb = (long)((li*2+dir)*64 + q)*192 + 128 + j0;
        float v[16];
        ld8<BF>(grr, sb, v);
        ld8<BF>(grr, sb+8, v+8);
        float* dp = sm + XTRA + dir*4096 + (q>>2)*256 + (q&3);
        #pragma unroll
        for (int j=0;j<16;++j) dp[(j0+j)*4] = v[j];
      }
      float rza[64], rra[64];
      float kc[64];
      float hmy=0, brz=0, brr=0, brh=0, bi=0;
      int hdir = 0, hgg = 0;
      const int dirw = (tid>>6)&1, jl = tid&63;
      if (tid < 128){
        long rb = (long)((li*2+dirw)*64)*192;
        #pragma unroll
        for (int q=0; q<64; ++q){
          rza[q] = ldf<BF>(grr, rb + (long)q*192 +      jl);
          rra[q] = ldf<BF>(grr, rb + (long)q*192 + 64 + jl);
        }
        long bb = (long)((li*2+dirw)*2+1)*192;
        brz = ldf<BF>(gbb, bb+jl); brr = ldf<BF>(gbb, bb+64+jl); brh = ldf<BF>(gbb, bb+128+jl);
        hmy = sm[O_MST + (li*2+dirw)*64 + jl];
        sm[HBUF + dirw*64 + jl] = hmy;
      } else {
        int c = tid-128; hdir = (c>=192); hgg = c - hdir*192;
        long kb = (long)((li*2+hdir)*64)*192;
        #pragma unroll
        for (int q=0; q<64; ++q) kc[q] = ldf<BF>(gk, kb + (long)q*192 + hgg);
        bi = ldf<BF>(gbb, (long)((li*2+hdir)*2)*192 + hgg);
      }
      __syncthreads();
      if (tid >= 128){ int c = tid-128;
        for (int pre=0; pre<2; ++pre){
          int xi = hdir ? (63-pre) : pre;
          const float* XP = sm + O_D0T + xi*68;
          float a = bi;
          #pragma unroll
          for (int k=0;k<16;++k){
            float4 xv = *(const float4*)(XP + 4*k);
            a += xv.x*kc[4*k] + xv.y*kc[4*k+1] + xv.z*kc[4*k+2] + xv.w*kc[4*k+3];
          }
          sm[XGR + pre*384 + c] = a; } }
      __syncthreads();
      for (int t=0; t<64; ++t){
        if (tid < 128){
          const float* ring = sm + XGR + (t&3)*384 + dirw*192;
          float xz = ring[jl], xr = ring[64+jl], xh = ring[128+jl];
          float az = brz, ar = brr, hh = brh;
          const float* HP = sm + HBUF + dirw*64;
          const float* WH = sm + XTRA + dirw*4096 + jl*4;
          #pragma unroll
          for (int k=0;k<16;++k){
            float4 hv = *(const float4*)(HP + 4*k);
            float4 wv = *(const float4*)(WH + k*256);
            az += hv.x*rza[4*k] + hv.y*rza[4*k+1] + hv.z*rza[4*k+2] + hv.w*rza[4*k+3];
            ar += hv.x*rra[4*k] + hv.y*rra[4*k+1] + hv.z*rra[4*k+2] + hv.w*rra[4*k+3];
            hh += hv.x*wv.x + hv.y*wv.y + hv.z*wv.z + hv.w*wv.w;
          }
          az += xz; ar += xr;
          float z  = 1.f/(1.f + __expf(-az));
          float rt = 1.f/(1.f + __expf(-ar));
          float ca = xh + rt*hh; ca = fminf(fmaxf(ca, -15.f), 15.f);
          float e2 = __expf(2.f*ca);
          float cand = (e2-1.f)/(e2+1.f);
          float hn = z*hmy + (1.f-z)*cand;
          hmy = hn;
          sm[O_BIG + (dirw*64+jl)*68 + t] = hn;
          sm[HBUF + dirw*64 + jl] = hn;
        } else if (t+2 < 64){
          int c = tid-128, pre = t+2;
          int xi = hdir ? (63-pre) : pre;
          const float* XP = sm + O_D0T + xi*68;
          float a = bi;
          #pragma unroll
          for (int k=0;k<16;++k){
            float4 xv = *(const float4*)(XP + 4*k);
            a += xv.x*kc[4*k] + xv.y*kc[4*k+1] + xv.z*kc[4*k+2] + xv.w*kc[4*k+3];
          }
          sm[XGR + ((t+2)&3)*384 + c] = a;
        }
        __syncthreads();
      }
      if (tid < 128) sm[O_MST + (li*2+dirw)*64 + jl] = hmy;
      __syncthreads();
    }

    //================= Stage E: MHA1 + ff + LN -> d1 in O_LAST =================
    mha_ff_ln<BF>(sm, li, 1, 128, qw, qb, ow, ob, ffw, ang, anb);

    //================= Stage G: bypass + skip LNs =================
    if ((li&1) == 0){
      float* bp = bypass + ((long)b*4 + (li>>1))*4096;
      for (int o=tid*4; o<4096; o+=TPB*4)
        *(float4*)(bp + o) = *(const float4*)(sm + O_LAST + o);
    }
    __syncthreads();
    { int jmp = 1, sidx = 0;
      while (((li+1) % jmp) == 0){
        int src = li - jmp + 1;
        { int r = tid>>3, prt = tid&7;
          const float4* Lv = (const float4*)(sm + O_LAST + r*64 + prt*8);
          float4 l0 = Lv[0], l1 = Lv[1];
          float Lr[8] = {l0.x,l0.y,l0.z,l0.w,l1.x,l1.y,l1.z,l1.w};
          float av[8];
          if (src == li){
            #pragma unroll
            for (int e=0;e<8;++e) av[e] = Lr[e];
          } else {
            const float4* bpr = (const float4*)(bypass + ((long)b*4 + (src>>1))*4096 + r*64 + prt*8);
            float4 b0 = bpr[0], b1 = bpr[1];
            av[0]=b0.x; av[1]=b0.y; av[2]=b0.z; av[3]=b0.w;
            av[4]=b1.x; av[5]=b1.y; av[6]=b1.z; av[7]=b1.w;
          }
          float f[8]; float s1=0, s2=0;
          #pragma unroll
          for (int e=0; e<8; ++e){ float fv = av[e] + Lr[e]; f[e]=fv; s1+=fv; s2+=fv*fv; }
          s1 += __shfl_xor(s1,4); s1 += __shfl_xor(s1,2); s1 += __shfl_xor(s1,1);
          s2 += __shfl_xor(s2,4); s2 += __shfl_xor(s2,2); s2 += __shfl_xor(s2,1);
          float mean = s1*0.015625f, var = s2*0.015625f - mean*mean;
          float rstd = rsqrtf(var + 1e-3f);
          long gb2 = (long)(li*4 + sidx)*64 + prt*8;
          float g[8], bbv[8];
          ldw4<BF>(sg,  gb2,   g[0],g[1],g[2],g[3]);     ldw4<BF>(sg,  gb2+4, g[4],g[5],g[6],g[7]);
          ldw4<BF>(sb2, gb2,   bbv[0],bbv[1],bbv[2],bbv[3]); ldw4<BF>(sb2, gb2+4, bbv[4],bbv[5],bbv[6],bbv[7]);
          float* W = sm + O_LAST + r*64 + prt*8;
          #pragma unroll
          for (int e=0; e<8; ++e) W[e] = (f[e]-mean)*rstd*g[e] + bbv[e];
        }
        jmp *= 2; ++sidx;
        __syncthreads();
      } }
  } // layers

  for (int o=tid; o<5120; o+=TPB){
    int p = o/80, d = o - p*80;
    float v = (d<64) ? sm[O_LAST + p*64 + d] : sm[O_MST + (d-64)*64 + p];
    stf<BF>(outp, (long)b*5120 + o, v);
  }
  for (int o=tid; o<1024; o+=TPB)
    stf<BF>(outp, (long)256*5120 + (long)b*1024 + o, sm[O_MST+o]);
}

// dtype sniffer: an_g ~= 1.0 +- 0.02 in both u16 halves iff bf16 storage.
__global__ void detect_dtype(const void* ang, int* flag){
  if (threadIdx.x == 0 && blockIdx.x == 0){
    const unsigned* w = (const unsigned*)ang;
    int good = 0;
    for (int k=0; k<64; ++k){
      unsigned u = w[k];
      float lo = __builtin_bit_cast(float, (u & 0xFFFFu) << 16);
      float hi = __builtin_bit_cast(float, u & 0xFFFF0000u);
      if (lo > 0.7f && lo < 1.4f && hi > 0.7f && hi < 1.4f) ++good;
    }
    *flag = (good >= 48) ? 1 : 0;
  }
}

__global__ void __launch_bounds__(TPB, 2) converter_kernel(
    const void* x, const void* st, const void* cw4, const void* cw3, const void* cw2,
    const void* cw1, const void* cb, const void* qw, const void* qb, const void* ow,
    const void* ob, const void* ffw, const void* ang, const void* anb, const void* gk,
    const void* grr, const void* gbb, const void* sg, const void* sb2,
    const int* flagp, void* outp, float* bypass)
{
  extern __shared__ float sm[];
  if (*flagp)
    run_all<1>(sm, x, st, cw4, cw3, cw2, cw1, cb, qw, qb, ow, ob, ffw, ang, anb,
               gk, grr, gbb, sg, sb2, outp, bypass);
  else
    run_all<0>(sm, x, st, cw4, cw3, cw2, cw1, cb, qw, qb, ow, ob, ffw, ang, anb,
               gk, grr, gbb, sg, sb2, outp, bypass);
}

extern "C" void kernel_launch(void* const* d_in, const int* in_sizes, int n_in,
                              void* d_out, int out_size, void* d_ws, size_t ws_size,
                              hipStream_t stream) {
  (void)in_sizes; (void)n_in; (void)out_size; (void)ws_size;
  int*   flag   = (int*)d_ws;
  float* bypass = (float*)((char*)d_ws + 256);   // 256*4*4096 f32 = 16.8 MB

  hipFuncSetAttribute(reinterpret_cast<const void*>(converter_kernel),
                      hipFuncAttributeMaxDynamicSharedMemorySize, SMF*4);

  detect_dtype<<<1, 64, 0, stream>>>(d_in[12], flag);
  converter_kernel<<<256, TPB, SMF*4, stream>>>(
      d_in[0], d_in[1], d_in[2], d_in[3], d_in[4], d_in[5], d_in[6], d_in[7],
      d_in[8], d_in[9], d_in[10], d_in[11], d_in[12], d_in[13], d_in[14],
      d_in[15], d_in[16], d_in[17], d_in[18], flag, d_out, bypass);
}